// Round 2
// baseline (7168.048 us; speedup 1.0000x reference)
//
#include <hip/hip_runtime.h>
#include <math.h>

#define NCODES 1024
#define DIM    256
#define BB     64
#define HH     32
#define WW     32
#define NROWS  (BB * HH * WW)      // 65536
#define RPB    32                  // rows per block (one (b,h) pair)
#define NBLK   (NROWS / RPB)       // 2048
#define ZQ_ELEMS (BB * DIM * HH * WW)  // 16777216
#define LDSTRIDE 260               // 256 + 4 pad: 16B-aligned rows, conflict-free reads

// ---- kernel 1: codebook norms B_k = ||e_k||^2 (f64 accum -> f32); zero counts ----
__global__ __launch_bounds__(64) void vq_norms(const float* __restrict__ cb,
                                               float* __restrict__ q,
                                               int* __restrict__ counts) {
    int k = blockIdx.x;
    int lane = threadIdx.x;
    float4 e4 = *(const float4*)(cb + (size_t)k * DIM + lane * 4);
    double s = (double)e4.x * e4.x + (double)e4.y * e4.y
             + (double)e4.z * e4.z + (double)e4.w * e4.w;
    #pragma unroll
    for (int off = 32; off > 0; off >>= 1) s += __shfl_down(s, off);
    if (lane == 0) {
        q[k] = (float)s;
        counts[k] = 0;   // reset histogram every call (deterministic)
    }
}

// ---- kernel 2: argmin with np-f32-replicated rounding + gather + loss + histogram ----
__global__ __launch_bounds__(256) void vq_main(const float* __restrict__ z,
                                               const float* __restrict__ cb,
                                               const float* __restrict__ q,
                                               float* __restrict__ out_zq,
                                               float* __restrict__ out_idx,
                                               int* __restrict__ counts,
                                               float* __restrict__ lpart) {
    __shared__ float zt[RPB][LDSTRIDE];   // [w][d], transposed z tile
    __shared__ float sbest[RPB][8];
    __shared__ int   kbest[RPB][8];
    __shared__ int   sel[RPB];
    __shared__ float lred[256];

    const int blk = blockIdx.x;           // b*32 + h
    const int b   = blk >> 5;
    const int h   = blk & 31;
    const int tid = threadIdx.x;

    const float* zb = z + (size_t)b * DIM * HH * WW + (size_t)h * WW;

    // stage z[b, :, h, :] into LDS transposed: zt[w][d]
    #pragma unroll
    for (int it = 0; it < 32; ++it) {
        int e = it * 256 + tid;
        int d = e >> 5;
        int w = e & 31;
        zt[w][d] = zb[(size_t)d * (HH * WW) + w];
    }
    __syncthreads();

    // each thread: row r = tid>>3, code lane = tid&7, codes k = lane + 8j
    const int r    = tid >> 3;
    const int lane = tid & 7;
    const float4* zr = (const float4*)(&zt[r][0]);   // row 16B-aligned (1040B stride)

    // A = ||z_row||^2, f64 accumulation -> f32. Exact rounding of A is
    // argmin-neutral (uniform shift across k), so summation order is free.
    double pa = 0.0;
    #pragma unroll 8
    for (int i = 0; i < 32; ++i) {
        float v = zt[r][lane + 8 * i];
        pa += (double)v * (double)v;
    }
    pa += __shfl_down(pa, 4, 8);
    pa += __shfl_down(pa, 2, 8);
    pa += __shfl_down(pa, 1, 8);
    pa = __shfl(pa, 0, 8);               // broadcast within the row's 8 lanes
    const float A = (float)pa;

    float best = INFINITY;
    int   bk   = 0;

    for (int j = 0; j < 64; ++j) {
        const int k1 = lane + 8 * j;
        const int k2 = k1 + 512;
        const float4* e1 = (const float4*)(cb + (size_t)k1 * DIM);
        const float4* e2 = (const float4*)(cb + (size_t)k2 * DIM);
        // 4 FMA chains per dot (BLAS-like error scale ~2e-9)
        float a1x = 0.f, a1y = 0.f, a1z = 0.f, a1w = 0.f;
        float a2x = 0.f, a2y = 0.f, a2z = 0.f, a2w = 0.f;
        #pragma unroll 16
        for (int d4 = 0; d4 < DIM / 4; ++d4) {
            float4 zv = zr[d4];
            float4 v1 = e1[d4];
            float4 v2 = e2[d4];
            a1x = fmaf(zv.x, v1.x, a1x);
            a1y = fmaf(zv.y, v1.y, a1y);
            a1z = fmaf(zv.z, v1.z, a1z);
            a1w = fmaf(zv.w, v1.w, a1w);
            a2x = fmaf(zv.x, v2.x, a2x);
            a2y = fmaf(zv.y, v2.y, a2y);
            a2z = fmaf(zv.z, v2.z, a2z);
            a2w = fmaf(zv.w, v2.w, a2w);
        }
        float dot1 = __fadd_rn(__fadd_rn(a1x, a1y), __fadd_rn(a1z, a1w));
        float dot2 = __fadd_rn(__fadd_rn(a2x, a2y), __fadd_rn(a2z, a2w));
        // replicate np's f32 pipeline: fl( fl(A + B_k) - fl(2*dot) )
        // _rn intrinsics block fp-contract from fusing the 2*dot into the sub.
        float s1 = __fsub_rn(__fadd_rn(A, q[k1]), __fmul_rn(2.f, dot1));
        float s2 = __fsub_rn(__fadd_rn(A, q[k2]), __fmul_rn(2.f, dot2));
        if (s1 < best || (s1 == best && k1 < bk)) { best = s1; bk = k1; }
        if (s2 < best || (s2 == best && k2 < bk)) { best = s2; bk = k2; }
    }
    sbest[r][lane] = best;
    kbest[r][lane] = bk;
    __syncthreads();

    // per-row final argmin over 8 lanes (lowest index on ties = np first-occurrence)
    if (tid < RPB) {
        float bb = sbest[tid][0];
        int   bi = kbest[tid][0];
        #pragma unroll
        for (int l = 1; l < 8; ++l) {
            float s  = sbest[tid][l];
            int   kk = kbest[tid][l];
            if (s < bb || (s == bb && kk < bi)) { bb = s; bi = kk; }
        }
        sel[tid] = bi;
        out_idx[blk * RPB + tid] = (float)bi;
        atomicAdd(&counts[bi], 1);
    }
    __syncthreads();

    // gather z_q into out (same layout as z) + commitment-loss partial
    float lacc = 0.f;
    float* ob = out_zq + (size_t)b * DIM * HH * WW + (size_t)h * WW;
    #pragma unroll
    for (int it = 0; it < 32; ++it) {
        int e = it * 256 + tid;
        int c = e >> 5;
        int w = e & 31;
        float cv = cb[(size_t)sel[w] * DIM + c];
        float dz = cv - zt[w][c];
        lacc = fmaf(dz, dz, lacc);
        ob[(size_t)c * (HH * WW) + w] = cv;
    }

    lred[tid] = lacc;
    __syncthreads();
    #pragma unroll
    for (int s = 128; s > 0; s >>= 1) {
        if (tid < s) lred[tid] += lred[tid + s];
        __syncthreads();
    }
    if (tid == 0) lpart[blk] = lred[0];
}

// ---- kernel 3: scalars (loss, perplexity), deterministic f64 reduce ----
__global__ __launch_bounds__(256) void vq_finalize(const float* __restrict__ lpart,
                                                   const int* __restrict__ counts,
                                                   float* __restrict__ out_scalars) {
    __shared__ double sd[256];
    const int tid = threadIdx.x;

    double s = 0.0;
    for (int i = tid; i < NBLK; i += 256) s += (double)lpart[i];
    sd[tid] = s;
    __syncthreads();
    #pragma unroll
    for (int st = 128; st > 0; st >>= 1) {
        if (tid < st) sd[tid] += sd[tid + st];
        __syncthreads();
    }
    double loss = 0.0;
    if (tid == 0) loss = 0.25 * sd[0] / (double)ZQ_ELEMS;
    __syncthreads();

    double e = 0.0;
    for (int i = tid; i < NCODES; i += 256) {
        float p = (float)counts[i] / (float)NROWS;
        e += (double)(p * logf(p + 1e-10f));
    }
    sd[tid] = e;
    __syncthreads();
    #pragma unroll
    for (int st = 128; st > 0; st >>= 1) {
        if (tid < st) sd[tid] += sd[tid + st];
        __syncthreads();
    }
    if (tid == 0) {
        out_scalars[0] = (float)loss;
        out_scalars[1] = expf((float)(-sd[0]));
    }
}

extern "C" void kernel_launch(void* const* d_in, const int* in_sizes, int n_in,
                              void* d_out, int out_size, void* d_ws, size_t ws_size,
                              hipStream_t stream) {
    const float* z  = (const float*)d_in[0];          // [64,256,32,32]
    const float* cb = (const float*)d_in[1];          // [1024,256]

    float* out_zq      = (float*)d_out;               // 16777216
    float* out_idx     = out_zq + ZQ_ELEMS;           // 65536 (indices as float)
    float* out_scalars = out_idx + NROWS;             // loss, perplexity

    float* q      = (float*)d_ws;                     // 1024 f32
    int*   counts = (int*)(q + NCODES);               // 1024 i32
    float* lpart  = (float*)(counts + NCODES);        // 2048 f32

    vq_norms<<<NCODES, 64, 0, stream>>>(cb, q, counts);
    vq_main<<<NBLK, 256, 0, stream>>>(z, cb, q, out_zq, out_idx, counts, lpart);
    vq_finalize<<<1, 256, 0, stream>>>(lpart, counts, out_scalars);
}

// Round 3
// 339.089 us; speedup vs baseline: 21.1391x; 21.1391x over previous
//
#include <hip/hip_runtime.h>
#include <math.h>
#include <stdint.h>

#define NCODES   1024
#define DIM      256
#define NROWS    65536
#define ZQ_ELEMS 16777216
#define MARGIN   1.2e-3f
#define LDSTRIDE 260

typedef _Float16 f16x8 __attribute__((ext_vector_type(8)));
typedef float    f32x4 __attribute__((ext_vector_type(4)));

__device__ __forceinline__ void gload16(void* lds, const void* g) {
  __builtin_amdgcn_global_load_lds(
      (const __attribute__((address_space(1))) uint32_t*)g,
      (__attribute__((address_space(3))) uint32_t*)lds, 16, 0, 0);
}

// ---- prep: codebook norms (f64->f32), zero counts, f32->f16 codebook ----
__global__ __launch_bounds__(64) void vq_prep(const float* __restrict__ cb,
                                              float* __restrict__ cbnorm,
                                              int* __restrict__ counts,
                                              ushort* __restrict__ cbh) {
    int k = blockIdx.x, l = threadIdx.x;
    float4 e4 = *(const float4*)(cb + (size_t)k * DIM + l * 4);
    double s = (double)e4.x * e4.x + (double)e4.y * e4.y
             + (double)e4.z * e4.z + (double)e4.w * e4.w;
    #pragma unroll
    for (int off = 32; off > 0; off >>= 1) s += __shfl_down(s, off);
    _Float16 hx = (_Float16)e4.x, hy = (_Float16)e4.y,
             hz = (_Float16)e4.z, hw = (_Float16)e4.w;
    ushort4 u4;
    u4.x = __builtin_bit_cast(unsigned short, hx);
    u4.y = __builtin_bit_cast(unsigned short, hy);
    u4.z = __builtin_bit_cast(unsigned short, hz);
    u4.w = __builtin_bit_cast(unsigned short, hw);
    *(ushort4*)(cbh + (size_t)k * DIM + l * 4) = u4;
    if (l == 0) { cbnorm[k] = (float)s; counts[k] = 0; }
}

// ---- main: MFMA filter + exact rescore + gather + loss + histogram ----
__global__ __launch_bounds__(512, 2) void vq_mfma(
    const float* __restrict__ z, const float* __restrict__ cb,
    const ushort* __restrict__ cbh, const float* __restrict__ cbnorm,
    float* __restrict__ out_zq, float* __restrict__ out_idx,
    int* __restrict__ counts, float* __restrict__ lpart)
{
    __shared__ float zt[64 * 256];       // elem (r,c) at zt[r*256 + (c ^ (r&31))]
    __shared__ union {
        ushort bt[2][64 * 256];          // f16 B tiles, slot-swizzled
        struct {
            float rrm1[64][4]; int rrk[64][4]; float rrm2[64][4];
            float wrs[64][4];  int wrk[64][4]; int wrov[64][4];
            float As[64]; float thr[64]; int amb[64]; int fb[64]; int sel[64];
            float redS[8]; int redK[8]; float wsum[8];
        } s;
    } u;

    const int tid = threadIdx.x;
    const int w   = tid >> 6, l = tid & 63;
    const int g   = l >> 4,  m = l & 15;
    const int wm  = w >> 2,  wn = w & 3;
    const int blk = blockIdx.x;          // 1024 blocks, 64 rows each
    const int n0  = blk << 6;
    const int b     = blk >> 4;
    const int hpair = blk & 15;

    const float* zb = z + (size_t)b * 262144 + hpair * 64;

    // issue stage of B tile 0 into buf 0 (async, lands before first barrier)
    #pragma unroll
    for (int rho = 0; rho < 4; ++rho) {
        int n = rho * 16 + (w << 1) + (l >> 5);
        int sl = l & 31;
        const ushort* src = cbh + (size_t)n * 256 + ((sl ^ (n & 7)) << 3);
        gload16(&u.bt[0][rho * 4096 + w * 512], src);
    }

    // stage z rows [n0, n0+64) transposed+swizzled; coalesced along r
    #pragma unroll 4
    for (int it = 0; it < 32; ++it) {
        int e = it * 512 + tid;
        int c = e >> 6, r = e & 63;
        zt[r * 256 + (c ^ (r & 31))] = zb[(size_t)c * 1024 + r];
    }
    __syncthreads();

    // A fragments (f16) for this wave's 2 row-groups
    f16x8 afrag[2][8];
    #pragma unroll
    for (int a = 0; a < 2; ++a) {
        int row = (wm * 2 + a) * 16 + m;
        int rx = row & 31;
        #pragma unroll
        for (int t = 0; t < 8; ++t) {
            f16x8 f;
            #pragma unroll
            for (int j = 0; j < 8; ++j) {
                int c = t * 32 + g * 8 + j;
                f[j] = (_Float16)zt[row * 256 + (c ^ rx)];
            }
            afrag[a][t] = f;
        }
    }

    // per-lane top-2(+3rd value) tracking per row-slot
    float s1[8], s2v[8], s3v[8]; int k1[8], k2[8];
    #pragma unroll
    for (int i = 0; i < 8; ++i) {
        s1[i] = INFINITY; s2v[i] = INFINITY; s3v[i] = INFINITY; k1[i] = 0; k2[i] = 0;
    }

    const int nB = wn * 16 + m;      // B col within 64-code tile
    const int nx = nB & 7;

    int cur = 0;
    for (int tt = 0; tt < 16; ++tt) {
        if (tt < 15) {
            #pragma unroll
            for (int rho = 0; rho < 4; ++rho) {
                int n = rho * 16 + (w << 1) + (l >> 5);
                int sl = l & 31;
                const ushort* src = cbh + (size_t)((tt + 1) * 64 + n) * 256
                                        + ((sl ^ (n & 7)) << 3);
                gload16(&u.bt[cur ^ 1][rho * 4096 + w * 512], src);
            }
        }
        f32x4 acc0 = {0.f, 0.f, 0.f, 0.f}, acc1 = {0.f, 0.f, 0.f, 0.f};
        const ushort* bt = u.bt[cur];
        #pragma unroll
        for (int t = 0; t < 8; ++t) {
            f16x8 bf = *(const f16x8*)(bt + nB * 256 + (((4 * t + g) ^ nx) << 3));
            acc0 = __builtin_amdgcn_mfma_f32_16x16x32_f16(afrag[0][t], bf, acc0, 0, 0, 0);
            acc1 = __builtin_amdgcn_mfma_f32_16x16x32_f16(afrag[1][t], bf, acc1, 0, 0, 0);
        }
        int k = tt * 64 + nB;
        float qk = cbnorm[k];
        #pragma unroll
        for (int a = 0; a < 2; ++a) {
            #pragma unroll
            for (int j = 0; j < 4; ++j) {
                float sc = fmaf(-2.f, (a ? acc1[j] : acc0[j]), qk);
                int si = a * 4 + j;
                if (sc < s3v[si]) {
                    if (sc < s2v[si]) {
                        s3v[si] = s2v[si];
                        if (sc < s1[si]) { s2v[si] = s1[si]; k2[si] = k1[si]; s1[si] = sc; k1[si] = k; }
                        else             { s2v[si] = sc; k2[si] = k; }
                    } else { s3v[si] = sc; }
                }
            }
        }
        __syncthreads();
        cur ^= 1;
    }

    // exact row norms A (f64 accum, same order as round-2 pipeline)
    {
        int r = tid >> 3, q8 = tid & 7;
        int rx = r & 31;
        double pa = 0.0;
        #pragma unroll 8
        for (int i = 0; i < 32; ++i) {
            float v = zt[r * 256 + ((q8 + 8 * i) ^ rx)];
            pa += (double)v * (double)v;
        }
        pa += __shfl_down(pa, 4, 8);
        pa += __shfl_down(pa, 2, 8);
        pa += __shfl_down(pa, 1, 8);
        if (q8 == 0) u.s.As[r] = (float)pa;
    }

    // per-wave two-min reduce per slot -> rr (wave covers 1/4 of codes)
    #pragma unroll
    for (int si = 0; si < 8; ++si) {
        float v1 = s1[si]; int kk = k1[si]; float v2 = s2v[si];
        #pragma unroll
        for (int mk = 1; mk < 16; mk <<= 1) {
            float o1 = __shfl_xor(v1, mk, 16);
            int   ok = __shfl_xor(kk, mk, 16);
            float o2 = __shfl_xor(v2, mk, 16);
            bool take = (o1 < v1) || (o1 == v1 && ok < kk);
            float nm2 = take ? fminf(v1, o2) : fminf(o1, v2);
            if (take) { v1 = o1; kk = ok; }
            v2 = nm2;
        }
        if ((l & 15) == 0) {
            int row = (wm * 2 + (si >> 2)) * 16 + g * 4 + (si & 3);
            u.s.rrm1[row][wn] = v1; u.s.rrk[row][wn] = kk; u.s.rrm2[row][wn] = v2;
        }
    }
    __syncthreads();

    // merge 4 wave-partials per row; decide skip vs ambiguous
    if (tid < 64) {
        float M1 = u.s.rrm1[tid][0]; int K1 = u.s.rrk[tid][0]; float M2 = u.s.rrm2[tid][0];
        #pragma unroll
        for (int q4 = 1; q4 < 4; ++q4) {
            float o1 = u.s.rrm1[tid][q4]; int ok = u.s.rrk[tid][q4]; float o2 = u.s.rrm2[tid][q4];
            bool take = (o1 < M1) || (o1 == M1 && ok < K1);
            float nm2 = take ? fminf(M1, o2) : fminf(o1, M2);
            if (take) { M1 = o1; K1 = ok; }
            M2 = nm2;
        }
        float th = M1 + MARGIN;
        int am = (M2 <= th) ? 1 : 0;
        u.s.thr[tid] = th; u.s.amb[tid] = am; u.s.fb[tid] = 0;
        if (!am) u.s.sel[tid] = K1;
    }
    __syncthreads();

    // exact rescore (replicates np f32 pipeline bit-for-bit vs round-2)
    const float* __restrict__ cbp = cb;
    const float* __restrict__ qn  = cbnorm;
    auto rescore = [&](int row, int k) -> float {
        const float* e  = cbp + (size_t)k * 256;
        const float* zr = zt + row * 256;
        int rx = row & 31;
        float ax = 0.f, ay = 0.f, az = 0.f, aw = 0.f;
        #pragma unroll 8
        for (int d4 = 0; d4 < 64; ++d4) {
            float4 ev = *(const float4*)(e + d4 * 4);
            int c0 = d4 * 4;
            ax = fmaf(zr[(c0    ) ^ rx], ev.x, ax);
            ay = fmaf(zr[(c0 + 1) ^ rx], ev.y, ay);
            az = fmaf(zr[(c0 + 2) ^ rx], ev.z, az);
            aw = fmaf(zr[(c0 + 3) ^ rx], ev.w, aw);
        }
        float dot = __fadd_rn(__fadd_rn(ax, ay), __fadd_rn(az, aw));
        return __fsub_rn(__fadd_rn(u.s.As[row], qn[k]), __fmul_rn(2.f, dot));
    };

    #pragma unroll 1
    for (int si = 0; si < 8; ++si) {
        int row = (wm * 2 + (si >> 2)) * 16 + g * 4 + (si & 3);
        if (u.s.amb[row]) {
            float th = u.s.thr[row];
            float bs = INFINITY; int bk = 0x7fffffff;
            int ov = (s3v[si] <= th) ? 1 : 0;
            if (s1[si] <= th) { bs = rescore(row, k1[si]); bk = k1[si]; }
            if (s2v[si] <= th) {
                float ss = rescore(row, k2[si]);
                if (ss < bs || (ss == bs && k2[si] < bk)) { bs = ss; bk = k2[si]; }
            }
            #pragma unroll
            for (int mk = 1; mk < 16; mk <<= 1) {
                float os = __shfl_xor(bs, mk, 16);
                int   okk = __shfl_xor(bk, mk, 16);
                int   oov = __shfl_xor(ov, mk, 16);
                if (os < bs || (os == bs && okk < bk)) { bs = os; bk = okk; }
                ov |= oov;
            }
            if ((l & 15) == 0) { u.s.wrs[row][wn] = bs; u.s.wrk[row][wn] = bk; u.s.wrov[row][wn] = ov; }
        }
    }
    __syncthreads();

    if (tid < 64 && u.s.amb[tid]) {
        float bs = u.s.wrs[tid][0]; int bk = u.s.wrk[tid][0]; int ov = u.s.wrov[tid][0];
        #pragma unroll
        for (int q4 = 1; q4 < 4; ++q4) {
            float os = u.s.wrs[tid][q4]; int okk = u.s.wrk[tid][q4];
            if (os < bs || (os == bs && okk < bk)) { bs = os; bk = okk; }
            ov |= u.s.wrov[tid][q4];
        }
        if (ov) u.s.fb[tid] = 1; else u.s.sel[tid] = bk;
    }
    __syncthreads();

    // fallback: guaranteed-exact full scan for flagged rows (rare)
    for (int r = 0; r < 64; ++r) {
        if (u.s.fb[r]) {
            float bsf = INFINITY; int bkf = 0x7fffffff;
            for (int kk = tid; kk < NCODES; kk += 512) {
                float ss = rescore(r, kk);
                if (ss < bsf || (ss == bsf && kk < bkf)) { bsf = ss; bkf = kk; }
            }
            #pragma unroll
            for (int off = 32; off > 0; off >>= 1) {
                float os = __shfl_down(bsf, off); int okk = __shfl_down(bkf, off);
                if (os < bsf || (os == bsf && okk < bkf)) { bsf = os; bkf = okk; }
            }
            if (l == 0) { u.s.redS[w] = bsf; u.s.redK[w] = bkf; }
            __syncthreads();
            if (tid == 0) {
                float bs2 = u.s.redS[0]; int bk2 = u.s.redK[0];
                for (int i = 1; i < 8; ++i) {
                    float os = u.s.redS[i]; int okk = u.s.redK[i];
                    if (os < bs2 || (os == bs2 && okk < bk2)) { bs2 = os; bk2 = okk; }
                }
                u.s.sel[r] = bk2;
            }
            __syncthreads();
        }
    }

    // indices + histogram
    if (tid < 64) {
        int sv = u.s.sel[tid];
        out_idx[n0 + tid] = (float)sv;
        atomicAdd(&counts[sv], 1);
    }

    // gather z_q + commitment-loss partial
    float lacc = 0.f;
    float* ob = out_zq + (size_t)b * 262144 + hpair * 64;
    #pragma unroll 4
    for (int it = 0; it < 32; ++it) {
        int e = it * 512 + tid;
        int c = e >> 6, r = e & 63;
        float cv = cbp[(size_t)u.s.sel[r] * 256 + c];
        float zv = zt[r * 256 + (c ^ (r & 31))];
        float dz = cv - zv;
        lacc = fmaf(dz, dz, lacc);
        ob[(size_t)c * 1024 + r] = cv;
    }
    #pragma unroll
    for (int off = 32; off > 0; off >>= 1) lacc += __shfl_down(lacc, off);
    if (l == 0) u.s.wsum[w] = lacc;
    __syncthreads();
    if (tid == 0) {
        float t = 0.f;
        for (int i = 0; i < 8; ++i) t += u.s.wsum[i];
        lpart[blk] = t;
    }
}

// ---- finalize: loss + perplexity ----
__global__ __launch_bounds__(256) void vq_finalize(const float* __restrict__ lpart,
                                                   const int* __restrict__ counts,
                                                   float* __restrict__ out_scalars,
                                                   int nblk) {
    __shared__ double sd[256];
    const int tid = threadIdx.x;
    double s = 0.0;
    for (int i = tid; i < nblk; i += 256) s += (double)lpart[i];
    sd[tid] = s;
    __syncthreads();
    #pragma unroll
    for (int st = 128; st > 0; st >>= 1) {
        if (tid < st) sd[tid] += sd[tid + st];
        __syncthreads();
    }
    double loss = 0.0;
    if (tid == 0) loss = 0.25 * sd[0] / (double)ZQ_ELEMS;
    __syncthreads();
    double e = 0.0;
    for (int i = tid; i < NCODES; i += 256) {
        float p = (float)counts[i] / (float)NROWS;
        e += (double)(p * logf(p + 1e-10f));
    }
    sd[tid] = e;
    __syncthreads();
    #pragma unroll
    for (int st = 128; st > 0; st >>= 1) {
        if (tid < st) sd[tid] += sd[tid + st];
        __syncthreads();
    }
    if (tid == 0) {
        out_scalars[0] = (float)loss;
        out_scalars[1] = expf((float)(-sd[0]));
    }
}

// ================= round-2 fallback path (used only if ws too small) ========
__global__ __launch_bounds__(64) void vq_norms(const float* __restrict__ cb,
                                               float* __restrict__ q,
                                               int* __restrict__ counts) {
    int k = blockIdx.x;
    int lane = threadIdx.x;
    float4 e4 = *(const float4*)(cb + (size_t)k * DIM + lane * 4);
    double s = (double)e4.x * e4.x + (double)e4.y * e4.y
             + (double)e4.z * e4.z + (double)e4.w * e4.w;
    #pragma unroll
    for (int off = 32; off > 0; off >>= 1) s += __shfl_down(s, off);
    if (lane == 0) { q[k] = (float)s; counts[k] = 0; }
}

__global__ __launch_bounds__(256) void vq_main_r2(const float* __restrict__ z,
                                                  const float* __restrict__ cb,
                                                  const float* __restrict__ q,
                                                  float* __restrict__ out_zq,
                                                  float* __restrict__ out_idx,
                                                  int* __restrict__ counts,
                                                  float* __restrict__ lpart) {
    __shared__ float zt[32][LDSTRIDE];
    __shared__ float sbest[32][8];
    __shared__ int   kbest[32][8];
    __shared__ int   sel[32];
    __shared__ float lred[256];

    const int blk = blockIdx.x;
    const int b   = blk >> 5;
    const int h   = blk & 31;
    const int tid = threadIdx.x;
    const float* zb = z + (size_t)b * 262144 + (size_t)h * 32;

    #pragma unroll
    for (int it = 0; it < 32; ++it) {
        int e = it * 256 + tid;
        int d = e >> 5, w = e & 31;
        zt[w][d] = zb[(size_t)d * 1024 + w];
    }
    __syncthreads();

    const int r    = tid >> 3;
    const int lane = tid & 7;
    const float4* zr = (const float4*)(&zt[r][0]);

    double pa = 0.0;
    #pragma unroll 8
    for (int i = 0; i < 32; ++i) {
        float v = zt[r][lane + 8 * i];
        pa += (double)v * (double)v;
    }
    pa += __shfl_down(pa, 4, 8);
    pa += __shfl_down(pa, 2, 8);
    pa += __shfl_down(pa, 1, 8);
    pa = __shfl(pa, 0, 8);
    const float A = (float)pa;

    float best = INFINITY;
    int   bk   = 0;
    for (int j = 0; j < 64; ++j) {
        const int k1 = lane + 8 * j;
        const int k2 = k1 + 512;
        const float4* e1 = (const float4*)(cb + (size_t)k1 * DIM);
        const float4* e2 = (const float4*)(cb + (size_t)k2 * DIM);
        float a1x = 0.f, a1y = 0.f, a1z = 0.f, a1w = 0.f;
        float a2x = 0.f, a2y = 0.f, a2z = 0.f, a2w = 0.f;
        #pragma unroll 16
        for (int d4 = 0; d4 < DIM / 4; ++d4) {
            float4 zv = zr[d4];
            float4 v1 = e1[d4];
            float4 v2 = e2[d4];
            a1x = fmaf(zv.x, v1.x, a1x); a1y = fmaf(zv.y, v1.y, a1y);
            a1z = fmaf(zv.z, v1.z, a1z); a1w = fmaf(zv.w, v1.w, a1w);
            a2x = fmaf(zv.x, v2.x, a2x); a2y = fmaf(zv.y, v2.y, a2y);
            a2z = fmaf(zv.z, v2.z, a2z); a2w = fmaf(zv.w, v2.w, a2w);
        }
        float dot1 = __fadd_rn(__fadd_rn(a1x, a1y), __fadd_rn(a1z, a1w));
        float dot2 = __fadd_rn(__fadd_rn(a2x, a2y), __fadd_rn(a2z, a2w));
        float s1 = __fsub_rn(__fadd_rn(A, q[k1]), __fmul_rn(2.f, dot1));
        float s2 = __fsub_rn(__fadd_rn(A, q[k2]), __fmul_rn(2.f, dot2));
        if (s1 < best || (s1 == best && k1 < bk)) { best = s1; bk = k1; }
        if (s2 < best || (s2 == best && k2 < bk)) { best = s2; bk = k2; }
    }
    sbest[r][lane] = best;
    kbest[r][lane] = bk;
    __syncthreads();

    if (tid < 32) {
        float bb = sbest[tid][0];
        int   bi = kbest[tid][0];
        #pragma unroll
        for (int ll = 1; ll < 8; ++ll) {
            float s = sbest[tid][ll]; int kk = kbest[tid][ll];
            if (s < bb || (s == bb && kk < bi)) { bb = s; bi = kk; }
        }
        sel[tid] = bi;
        out_idx[blk * 32 + tid] = (float)bi;
        atomicAdd(&counts[bi], 1);
    }
    __syncthreads();

    float lacc = 0.f;
    float* ob = out_zq + (size_t)b * 262144 + (size_t)h * 32;
    #pragma unroll
    for (int it = 0; it < 32; ++it) {
        int e = it * 256 + tid;
        int c = e >> 5, w = e & 31;
        float cv = cb[(size_t)sel[w] * DIM + c];
        float dz = cv - zt[w][c];
        lacc = fmaf(dz, dz, lacc);
        ob[(size_t)c * 1024 + w] = cv;
    }
    lred[tid] = lacc;
    __syncthreads();
    #pragma unroll
    for (int s = 128; s > 0; s >>= 1) {
        if (tid < s) lred[tid] += lred[tid + s];
        __syncthreads();
    }
    if (tid == 0) lpart[blk] = lred[0];
}

extern "C" void kernel_launch(void* const* d_in, const int* in_sizes, int n_in,
                              void* d_out, int out_size, void* d_ws, size_t ws_size,
                              hipStream_t stream) {
    const float* z  = (const float*)d_in[0];          // [64,256,32,32]
    const float* cb = (const float*)d_in[1];          // [1024,256]

    float* out_zq      = (float*)d_out;               // 16777216
    float* out_idx     = out_zq + ZQ_ELEMS;           // 65536
    float* out_scalars = out_idx + NROWS;             // loss, perplexity

    float*  q      = (float*)d_ws;                    // 1024 f32
    int*    counts = (int*)(q + NCODES);              // 1024 i32
    float*  lpart  = (float*)(counts + NCODES);       // up to 2048 f32
    ushort* cbh    = (ushort*)((char*)d_ws + 16384);  // 512 KB f16 codebook

    bool mfma_ok = ws_size >= (size_t)(16384 + NCODES * DIM * 2);

    if (mfma_ok) {
        vq_prep<<<NCODES, 64, 0, stream>>>(cb, q, counts, cbh);
        vq_mfma<<<NROWS / 64, 512, 0, stream>>>(z, cb, cbh, q, out_zq, out_idx, counts, lpart);
        vq_finalize<<<1, 256, 0, stream>>>(lpart, counts, out_scalars, NROWS / 64);
    } else {
        vq_norms<<<NCODES, 64, 0, stream>>>(cb, q, counts);
        vq_main_r2<<<NROWS / 32, 256, 0, stream>>>(z, cb, q, out_zq, out_idx, counts, lpart);
        vq_finalize<<<1, 256, 0, stream>>>(lpart, counts, out_scalars, NROWS / 32);
    }
}

// Round 4
// 235.712 us; speedup vs baseline: 30.4102x; 1.4386x over previous
//
#include <hip/hip_runtime.h>
#include <math.h>
#include <stdint.h>

#define NCODES   1024
#define DIM      256
#define NROWS    65536
#define ZQ_ELEMS 16777216
#define MARGIN   1.2e-3f
#define LDSTRIDE 260

typedef _Float16 f16x8 __attribute__((ext_vector_type(8)));
typedef float    f32x4 __attribute__((ext_vector_type(4)));

// ---- prep: codebook norms (f64->f32, exact same order as r2/r3), zero
// counts, and f16 codebook in MFMA-fragment-linear layout ----
// frag chunk index = ((tt*4+cg)*8 + t)*64 + (g*16+m), 8 f16 per chunk, where
// k = tt*64+cg*16+m, dim = t*32+g*8+j.
__global__ __launch_bounds__(64) void vq_prep(const float* __restrict__ cb,
                                              float* __restrict__ cbnorm,
                                              int* __restrict__ counts,
                                              ushort* __restrict__ cbf) {
    int k = blockIdx.x, l = threadIdx.x;
    float4 e4 = *(const float4*)(cb + (size_t)k * DIM + l * 4);
    double s = (double)e4.x * e4.x + (double)e4.y * e4.y
             + (double)e4.z * e4.z + (double)e4.w * e4.w;
    #pragma unroll
    for (int off = 32; off > 0; off >>= 1) s += __shfl_down(s, off);

    // frag-linear pack: this thread owns dims 4l..4l+3 of code k
    int tt = k >> 6, cg = (k >> 4) & 3, m = k & 15;
    int dim0 = 4 * l;
    int t = dim0 >> 5, g = (dim0 >> 3) & 3, j0 = dim0 & 7;   // j0 in {0,4}
    int chunk = ((tt * 4 + cg) * 8 + t) * 64 + g * 16 + m;
    ushort4 u4;
    u4.x = __builtin_bit_cast(unsigned short, (_Float16)e4.x);
    u4.y = __builtin_bit_cast(unsigned short, (_Float16)e4.y);
    u4.z = __builtin_bit_cast(unsigned short, (_Float16)e4.z);
    u4.w = __builtin_bit_cast(unsigned short, (_Float16)e4.w);
    *(ushort4*)(cbf + (size_t)chunk * 8 + j0) = u4;

    if (l == 0) { cbnorm[k] = (float)s; counts[k] = 0; }
}

// ---- main: barrier-free MFMA filter + worklist exact rescore ----
__global__ __launch_bounds__(256, 2) void vq_mfma2(
    const float* __restrict__ z, const float* __restrict__ cb,
    const ushort* __restrict__ cbf, const float* __restrict__ cbnorm,
    float* __restrict__ out_zq, float* __restrict__ out_idx,
    int* __restrict__ counts, float* __restrict__ lpart)
{
    __shared__ float zt[32 * 260];          // f32 z tile, pad 260 (exact path)
    __shared__ union UU {
        ushort zth[32 * 264];               // f16 z tile, pad 264 (16B-aligned rows)
        struct {
            float rrm1[32][4]; int rrk[32][4]; float rrm2[32][4];
            int wlRow[256]; int wlK[256]; float wlS[256];
        } p;
        float cbs[32 * 260];                // gathered codebook rows (output stage)
    } u;
    __shared__ float As[32], thr[32];
    __shared__ int amb[32], fb[32], sel[32];
    __shared__ int wlN, fbAll;
    __shared__ float redS[4]; __shared__ int redK[4]; __shared__ float wsum[4];

    const int tid = threadIdx.x;
    const int w = tid >> 6, l = tid & 63;
    const int g = l >> 4, m = l & 15;
    const int blk = blockIdx.x;             // b*32 + h ; rows = w-coordinate
    const int b = blk >> 5, h = blk & 31;
    const int kbase = w * 16 + m;           // this lane's code column

    const float* zb = z + (size_t)b * 262144 + (size_t)h * 32;

    f16x8 bA[8], bB[8];
    auto load_b = [&](int tt, f16x8 (&dst)[8]) {
        const ushort* src = cbf + (size_t)(tt * 4 + w) * 4096 + (size_t)l * 8;
        #pragma unroll
        for (int t = 0; t < 8; ++t) dst[t] = *(const f16x8*)(src + t * 512);
    };

    load_b(0, bA);   // deep prefetch of B tile 0 (completes by the barrier)

    // stage z: f32 -> zt (pad 260) and f16 -> zth (pad 264); coalesced float4
    #pragma unroll
    for (int it = 0; it < 8; ++it) {
        int e = it * 256 + tid;
        int c = e >> 3, r4 = e & 7;
        float4 v = *(const float4*)(zb + (size_t)c * 1024 + r4 * 4);
        int r0 = r4 * 4;
        zt[(r0    ) * 260 + c] = v.x;
        zt[(r0 + 1) * 260 + c] = v.y;
        zt[(r0 + 2) * 260 + c] = v.z;
        zt[(r0 + 3) * 260 + c] = v.w;
        u.zth[(r0    ) * 264 + c] = __builtin_bit_cast(unsigned short, (_Float16)v.x);
        u.zth[(r0 + 1) * 264 + c] = __builtin_bit_cast(unsigned short, (_Float16)v.y);
        u.zth[(r0 + 2) * 264 + c] = __builtin_bit_cast(unsigned short, (_Float16)v.z);
        u.zth[(r0 + 3) * 264 + c] = __builtin_bit_cast(unsigned short, (_Float16)v.w);
    }
    __syncthreads();

    // A fragments: rows m and 16+m, ds_read_b128 (rows 528B = 16B-aligned)
    f16x8 afrag0[8], afrag1[8];
    #pragma unroll
    for (int t = 0; t < 8; ++t) {
        afrag0[t] = *(const f16x8*)(&u.zth[(size_t)m * 264 + t * 32 + g * 8]);
        afrag1[t] = *(const f16x8*)(&u.zth[(size_t)(16 + m) * 264 + t * 32 + g * 8]);
    }

    float s1[8], s2[8]; int k1[8];
    #pragma unroll
    for (int i = 0; i < 8; ++i) { s1[i] = INFINITY; s2[i] = INFINITY; k1[i] = 0; }

    auto tile_body = [&](int tt, f16x8 (&bc)[8]) {
        f32x4 acc0 = {0.f, 0.f, 0.f, 0.f}, acc1 = {0.f, 0.f, 0.f, 0.f};
        #pragma unroll
        for (int t = 0; t < 8; ++t) {
            acc0 = __builtin_amdgcn_mfma_f32_16x16x32_f16(afrag0[t], bc[t], acc0, 0, 0, 0);
            acc1 = __builtin_amdgcn_mfma_f32_16x16x32_f16(afrag1[t], bc[t], acc1, 0, 0, 0);
        }
        const int kk = tt * 64 + kbase;
        const float qk = cbnorm[kk];
        #pragma unroll
        for (int j = 0; j < 4; ++j) {
            float sc = fmaf(-2.f, acc0[j], qk);
            float o = s1[j]; bool lt = sc < o;
            s1[j] = lt ? sc : o; k1[j] = lt ? kk : k1[j];
            s2[j] = fminf(s2[j], fmaxf(o, sc));
            float sd = fmaf(-2.f, acc1[j], qk);
            float o2 = s1[j + 4]; bool lt2 = sd < o2;
            s1[j + 4] = lt2 ? sd : o2; k1[j + 4] = lt2 ? kk : k1[j + 4];
            s2[j + 4] = fminf(s2[j + 4], fmaxf(o2, sd));
        }
    };

    // main loop: 16 tiles, B prefetched 1 tile ahead, NO barriers
    #pragma unroll 1
    for (int th2 = 0; th2 < 8; ++th2) {
        load_b(2 * th2 + 1, bB);
        tile_body(2 * th2, bA);
        if (th2 < 7) load_b(2 * th2 + 2, bA);
        tile_body(2 * th2 + 1, bB);
    }

    // exact row norms A (f64, bit-identical order to r2/r3 pipeline)
    {
        int r = tid >> 3, q8 = tid & 7;
        double pa = 0.0;
        #pragma unroll 8
        for (int i = 0; i < 32; ++i) {
            float v = zt[r * 260 + q8 + 8 * i];
            pa += (double)v * (double)v;
        }
        pa += __shfl_down(pa, 4, 8);
        pa += __shfl_down(pa, 2, 8);
        pa += __shfl_down(pa, 1, 8);
        if (q8 == 0) As[r] = (float)pa;
    }

    // per-slot two-min reduce over the 16 lanes sharing a row
    #pragma unroll
    for (int si = 0; si < 8; ++si) {
        float v1 = s1[si]; int kk = k1[si]; float v2 = s2[si];
        #pragma unroll
        for (int mk = 1; mk < 16; mk <<= 1) {
            float o1 = __shfl_xor(v1, mk, 16);
            int   ok = __shfl_xor(kk, mk, 16);
            float o2 = __shfl_xor(v2, mk, 16);
            bool take = (o1 < v1) || (o1 == v1 && ok < kk);
            float nm2 = fminf(fmaxf(o1, v1), fminf(o2, v2));
            if (take) { v1 = o1; kk = ok; }
            v2 = nm2;
        }
        if (m == 0) {
            int row = (si >> 2) * 16 + g * 4 + (si & 3);
            u.p.rrm1[row][w] = v1; u.p.rrk[row][w] = kk; u.p.rrm2[row][w] = v2;
        }
    }
    if (tid == 0) { wlN = 0; fbAll = 0; }
    __syncthreads();

    // merge 4 wave-partials per row; threshold & ambiguity
    if (tid < 32) {
        float M1 = u.p.rrm1[tid][0]; int K1 = u.p.rrk[tid][0]; float M2 = u.p.rrm2[tid][0];
        #pragma unroll
        for (int q4 = 1; q4 < 4; ++q4) {
            float o1 = u.p.rrm1[tid][q4]; int ok = u.p.rrk[tid][q4]; float o2 = u.p.rrm2[tid][q4];
            bool take = (o1 < M1) || (o1 == M1 && ok < K1);
            float nm2 = fminf(fmaxf(o1, M1), fminf(o2, M2));
            if (take) { M1 = o1; K1 = ok; }
            M2 = nm2;
        }
        float th_ = M1 + MARGIN;
        thr[tid] = th_; amb[tid] = (M2 <= th_) ? 1 : 0; fb[tid] = 0;
        sel[tid] = K1;                      // final for unambiguous rows
    }
    __syncthreads();

    // append in-margin candidates to worklist; lane-collision -> row fallback
    #pragma unroll
    for (int si = 0; si < 8; ++si) {
        int row = (si >> 2) * 16 + g * 4 + (si & 3);
        if (amb[row]) {
            float th_ = thr[row];
            if (s2[si] <= th_) fb[row] = 1;
            if (s1[si] <= th_) {
                int pos = atomicAdd(&wlN, 1);
                if (pos < 256) { u.p.wlRow[pos] = row; u.p.wlK[pos] = k1[si]; }
                else fbAll = 1;
            }
        }
    }
    __syncthreads();

    // exact rescore (bit-identical to the r2/r3 np-f32 pipeline)
    auto rescore = [&](int row, int k) -> float {
        const float* e  = cb + (size_t)k * 256;
        const float* zr = zt + row * 260;
        float ax = 0.f, ay = 0.f, az = 0.f, aw = 0.f;
        #pragma unroll 8
        for (int d4 = 0; d4 < 64; ++d4) {
            float4 ev = *(const float4*)(e + d4 * 4);
            ax = fmaf(zr[d4 * 4    ], ev.x, ax);
            ay = fmaf(zr[d4 * 4 + 1], ev.y, ay);
            az = fmaf(zr[d4 * 4 + 2], ev.z, az);
            aw = fmaf(zr[d4 * 4 + 3], ev.w, aw);
        }
        float dot = __fadd_rn(__fadd_rn(ax, ay), __fadd_rn(az, aw));
        return __fsub_rn(__fadd_rn(As[row], cbnorm[k]), __fmul_rn(2.f, dot));
    };

    int nw = wlN; nw = nw > 256 ? 256 : nw;
    for (int i = tid; i < nw; i += 256)
        u.p.wlS[i] = rescore(u.p.wlRow[i], u.p.wlK[i]);
    __syncthreads();

    // per-row merge of rescored candidates (min, lowest-k tie-break)
    if (tid < 32 && amb[tid]) {
        if (fbAll) fb[tid] = 1;
        if (!fb[tid]) {
            float bs = INFINITY; int bk = 0x7fffffff; int found = 0;
            for (int i = 0; i < nw; ++i) {
                if (u.p.wlRow[i] == tid) {
                    float ss = u.p.wlS[i]; int kk = u.p.wlK[i];
                    if (ss < bs || (ss == bs && kk < bk)) { bs = ss; bk = kk; }
                    found = 1;
                }
            }
            if (found) sel[tid] = bk; else fb[tid] = 1;
        }
    }
    __syncthreads();

    // fallback: guaranteed-exact full scan (rare; block-uniform branch)
    for (int r = 0; r < 32; ++r) {
        if (fb[r]) {
            float bsf = INFINITY; int bkf = 0x7fffffff;
            for (int kk = tid; kk < NCODES; kk += 256) {
                float ss = rescore(r, kk);
                if (ss < bsf || (ss == bsf && kk < bkf)) { bsf = ss; bkf = kk; }
            }
            #pragma unroll
            for (int off = 32; off > 0; off >>= 1) {
                float os = __shfl_down(bsf, off); int okk = __shfl_down(bkf, off);
                if (os < bsf || (os == bsf && okk < bkf)) { bsf = os; bkf = okk; }
            }
            if (l == 0) { redS[w] = bsf; redK[w] = bkf; }
            __syncthreads();
            if (tid == 0) {
                float bs2 = redS[0]; int bk2 = redK[0];
                for (int i = 1; i < 4; ++i) {
                    float os = redS[i]; int okk = redK[i];
                    if (os < bs2 || (os == bs2 && okk < bk2)) { bs2 = os; bk2 = okk; }
                }
                sel[r] = bk2;
            }
            __syncthreads();
        }
    }
    __syncthreads();

    // indices + histogram
    if (tid < 32) {
        int sv = sel[tid];
        out_idx[blk * 32 + tid] = (float)sv;
        atomicAdd(&counts[sv], 1);
    }

    // gather: coalesced codebook row reads -> cbs (zth is dead); fused loss
    float lacc = 0.f;
    #pragma unroll 1
    for (int ri = 0; ri < 8; ++ri) {
        int row = ri * 4 + w;
        int sv = sel[row];
        float4 cv = *(const float4*)(cb + (size_t)sv * 256 + l * 4);
        float4 zv = *(const float4*)(&zt[row * 260 + l * 4]);
        lacc = fmaf(cv.x - zv.x, cv.x - zv.x, lacc);
        lacc = fmaf(cv.y - zv.y, cv.y - zv.y, lacc);
        lacc = fmaf(cv.z - zv.z, cv.z - zv.z, lacc);
        lacc = fmaf(cv.w - zv.w, cv.w - zv.w, lacc);
        *(float4*)(&u.cbs[row * 260 + l * 4]) = cv;
    }
    #pragma unroll
    for (int off = 32; off > 0; off >>= 1) lacc += __shfl_down(lacc, off);
    if (l == 0) wsum[w] = lacc;
    __syncthreads();

    // coalesced output of z_q (transpose back through LDS)
    float* ob = out_zq + (size_t)b * 262144 + (size_t)h * 32;
    #pragma unroll 4
    for (int it = 0; it < 32; ++it) {
        int e = it * 256 + tid;
        int c = e >> 5, r = e & 31;
        ob[(size_t)c * 1024 + r] = u.cbs[r * 260 + c];
    }
    if (tid == 0) lpart[blk] = wsum[0] + wsum[1] + wsum[2] + wsum[3];
}

// ---- finalize: loss + perplexity ----
__global__ __launch_bounds__(256) void vq_finalize(const float* __restrict__ lpart,
                                                   const int* __restrict__ counts,
                                                   float* __restrict__ out_scalars,
                                                   int nblk) {
    __shared__ double sd[256];
    const int tid = threadIdx.x;
    double s = 0.0;
    for (int i = tid; i < nblk; i += 256) s += (double)lpart[i];
    sd[tid] = s;
    __syncthreads();
    #pragma unroll
    for (int st = 128; st > 0; st >>= 1) {
        if (tid < st) sd[tid] += sd[tid + st];
        __syncthreads();
    }
    double loss = 0.0;
    if (tid == 0) loss = 0.25 * sd[0] / (double)ZQ_ELEMS;
    __syncthreads();
    double e = 0.0;
    for (int i = tid; i < NCODES; i += 256) {
        float p = (float)counts[i] / (float)NROWS;
        e += (double)(p * logf(p + 1e-10f));
    }
    sd[tid] = e;
    __syncthreads();
    #pragma unroll
    for (int st = 128; st > 0; st >>= 1) {
        if (tid < st) sd[tid] += sd[tid + st];
        __syncthreads();
    }
    if (tid == 0) {
        out_scalars[0] = (float)loss;
        out_scalars[1] = expf((float)(-sd[0]));
    }
}

// ================= round-2 fallback path (used only if ws too small) ========
__global__ __launch_bounds__(64) void vq_norms(const float* __restrict__ cb,
                                               float* __restrict__ q,
                                               int* __restrict__ counts) {
    int k = blockIdx.x;
    int lane = threadIdx.x;
    float4 e4 = *(const float4*)(cb + (size_t)k * DIM + lane * 4);
    double s = (double)e4.x * e4.x + (double)e4.y * e4.y
             + (double)e4.z * e4.z + (double)e4.w * e4.w;
    #pragma unroll
    for (int off = 32; off > 0; off >>= 1) s += __shfl_down(s, off);
    if (lane == 0) { q[k] = (float)s; counts[k] = 0; }
}

__global__ __launch_bounds__(256) void vq_main_r2(const float* __restrict__ z,
                                                  const float* __restrict__ cb,
                                                  const float* __restrict__ q,
                                                  float* __restrict__ out_zq,
                                                  float* __restrict__ out_idx,
                                                  int* __restrict__ counts,
                                                  float* __restrict__ lpart) {
    __shared__ float zt[32][LDSTRIDE];
    __shared__ float sbest[32][8];
    __shared__ int   kbest[32][8];
    __shared__ int   sel[32];
    __shared__ float lred[256];

    const int blk = blockIdx.x;
    const int b   = blk >> 5;
    const int h   = blk & 31;
    const int tid = threadIdx.x;
    const float* zb = z + (size_t)b * 262144 + (size_t)h * 32;

    #pragma unroll
    for (int it = 0; it < 32; ++it) {
        int e = it * 256 + tid;
        int d = e >> 5, w = e & 31;
        zt[w][d] = zb[(size_t)d * 1024 + w];
    }
    __syncthreads();

    const int r    = tid >> 3;
    const int lane = tid & 7;
    const float4* zr = (const float4*)(&zt[r][0]);

    double pa = 0.0;
    #pragma unroll 8
    for (int i = 0; i < 32; ++i) {
        float v = zt[r][lane + 8 * i];
        pa += (double)v * (double)v;
    }
    pa += __shfl_down(pa, 4, 8);
    pa += __shfl_down(pa, 2, 8);
    pa += __shfl_down(pa, 1, 8);
    pa = __shfl(pa, 0, 8);
    const float A = (float)pa;

    float best = INFINITY;
    int   bk   = 0;
    for (int j = 0; j < 64; ++j) {
        const int k1 = lane + 8 * j;
        const int k2 = k1 + 512;
        const float4* e1 = (const float4*)(cb + (size_t)k1 * DIM);
        const float4* e2 = (const float4*)(cb + (size_t)k2 * DIM);
        float a1x = 0.f, a1y = 0.f, a1z = 0.f, a1w = 0.f;
        float a2x = 0.f, a2y = 0.f, a2z = 0.f, a2w = 0.f;
        #pragma unroll 16
        for (int d4 = 0; d4 < DIM / 4; ++d4) {
            float4 zv = zr[d4];
            float4 v1 = e1[d4];
            float4 v2 = e2[d4];
            a1x = fmaf(zv.x, v1.x, a1x); a1y = fmaf(zv.y, v1.y, a1y);
            a1z = fmaf(zv.z, v1.z, a1z); a1w = fmaf(zv.w, v1.w, a1w);
            a2x = fmaf(zv.x, v2.x, a2x); a2y = fmaf(zv.y, v2.y, a2y);
            a2z = fmaf(zv.z, v2.z, a2z); a2w = fmaf(zv.w, v2.w, a2w);
        }
        float dot1 = __fadd_rn(__fadd_rn(a1x, a1y), __fadd_rn(a1z, a1w));
        float dot2 = __fadd_rn(__fadd_rn(a2x, a2y), __fadd_rn(a2z, a2w));
        float s1 = __fsub_rn(__fadd_rn(A, q[k1]), __fmul_rn(2.f, dot1));
        float s2 = __fsub_rn(__fadd_rn(A, q[k2]), __fmul_rn(2.f, dot2));
        if (s1 < best || (s1 == best && k1 < bk)) { best = s1; bk = k1; }
        if (s2 < best || (s2 == best && k2 < bk)) { best = s2; bk = k2; }
    }
    sbest[r][lane] = best;
    kbest[r][lane] = bk;
    __syncthreads();

    if (tid < 32) {
        float bb = sbest[tid][0];
        int   bi = kbest[tid][0];
        #pragma unroll
        for (int ll = 1; ll < 8; ++ll) {
            float s = sbest[tid][ll]; int kk = kbest[tid][ll];
            if (s < bb || (s == bb && kk < bi)) { bb = s; bi = kk; }
        }
        sel[tid] = bi;
        out_idx[blk * 32 + tid] = (float)bi;
        atomicAdd(&counts[bi], 1);
    }
    __syncthreads();

    float lacc = 0.f;
    float* ob = out_zq + (size_t)b * 262144 + (size_t)h * 32;
    #pragma unroll
    for (int it = 0; it < 32; ++it) {
        int e = it * 256 + tid;
        int c = e >> 5, w = e & 31;
        float cv = cb[(size_t)sel[w] * DIM + c];
        float dz = cv - zt[w][c];
        lacc = fmaf(dz, dz, lacc);
        ob[(size_t)c * 1024 + w] = cv;
    }
    lred[tid] = lacc;
    __syncthreads();
    #pragma unroll
    for (int s = 128; s > 0; s >>= 1) {
        if (tid < s) lred[tid] += lred[tid + s];
        __syncthreads();
    }
    if (tid == 0) lpart[blk] = lred[0];
}

extern "C" void kernel_launch(void* const* d_in, const int* in_sizes, int n_in,
                              void* d_out, int out_size, void* d_ws, size_t ws_size,
                              hipStream_t stream) {
    const float* z  = (const float*)d_in[0];          // [64,256,32,32]
    const float* cb = (const float*)d_in[1];          // [1024,256]

    float* out_zq      = (float*)d_out;               // 16777216
    float* out_idx     = out_zq + ZQ_ELEMS;           // 65536
    float* out_scalars = out_idx + NROWS;             // loss, perplexity

    float*  q      = (float*)d_ws;                    // 1024 f32
    int*    counts = (int*)(q + NCODES);              // 1024 i32
    float*  lpart  = (float*)(counts + NCODES);       // 2048 f32
    ushort* cbf    = (ushort*)((char*)d_ws + 16384);  // 512 KB frag-linear f16

    bool mfma_ok = ws_size >= (size_t)(16384 + NCODES * DIM * 2);

    if (mfma_ok) {
        vq_prep<<<NCODES, 64, 0, stream>>>(cb, q, counts, cbf);
        vq_mfma2<<<NROWS / 32, 256, 0, stream>>>(z, cb, cbf, q, out_zq, out_idx, counts, lpart);
        vq_finalize<<<1, 256, 0, stream>>>(lpart, counts, out_scalars, NROWS / 32);
    } else {
        vq_norms<<<NCODES, 64, 0, stream>>>(cb, q, counts);
        vq_main_r2<<<NROWS / 32, 256, 0, stream>>>(z, cb, q, out_zq, out_idx, counts, lpart);
        vq_finalize<<<1, 256, 0, stream>>>(lpart, counts, out_scalars, NROWS / 32);
    }
}